// Round 8
// baseline (326.258 us; speedup 1.0000x reference)
//
#include <hip/hip_runtime.h>
#include <hip/hip_bf16.h>
#include <math.h>
#include <stdint.h>

// GCN 2-layer: h1 = relu(Agg(x@W1)+b1); out = log_softmax(Agg(h1@W2)+b2)
// Agg factorized: out[i] = dinv[i]*( sum_{e: col=i} hs[row_e] + hs[i] ) + b,
// hs[j] = dinv[j]*(x@W1)[j], fp8-e4m3 dense 32B rows (3.2MB L2-resident).
// R19: WHOLE pipeline in ONE normal kernel (2 dispatches: memset + mega).
// R18's cooperative launch silently no-oped under graph capture (out==0);
// replaced with a manual resident-grid spin barrier: 391 blocks x 512thr,
// launch_bounds(512,4) -> VGPR<=128, LDS 59.9KB -> 2 blocks/CU -> capacity
// 512 >= 391, all blocks co-resident => spin barrier is deadlock-free.
// __threadfence() release/acquire at the barrier gives cross-XCD visibility.
// Block b owns bucket b (256 nodes): buckets its 4096-edge chunk, matmuls its
// OWN nodes (h1 bf16 kept in LDS; h1b global DELETED), bar, sort+prescale
// (h1q = fp8(dinv*h1_lds)), bar, gather1 from LDS stage[], bar, gather2.
// Deleted vs R17: 3 launch+drain boundaries, slab writeback, h1b (12.8MB
// traffic), offsets[], dinv[], sorted_row[]. Numerics identical to R17.

#define GNN_N 100000
#define GNN_E 1600000
#define NBUCK 391     // buckets: col>>8 (256 nodes each); also the grid size
#define CAP 4608      // slab capacity (mean ~4092, +8 sigma)
#define CHB 4096      // edges per block chunk (8/thread at 512 thr)
#define XPAD 136      // 17*8: short8-aligned rows

typedef float fx2 __attribute__((ext_vector_type(2)));
typedef short short8x __attribute__((ext_vector_type(8)));
typedef float f32x4 __attribute__((ext_vector_type(4)));

__device__ inline uint16_t bf16_bits(float f) {   // RNE
    uint32_t u = __float_as_uint(f);
    return (uint16_t)((u + 0x7fffu + ((u >> 16) & 1u)) >> 16);
}
__device__ inline uint32_t pack_bf2(float lo, float hi) {
    return (uint32_t)bf16_bits(lo) | ((uint32_t)bf16_bits(hi) << 16);
}

// acc[0..15] += fp8x16 decoded from uint4
__device__ inline void fp8x16_acc(float* a, uint4 u) {
    fx2 p;
    p = __builtin_amdgcn_cvt_pk_f32_fp8(u.x, false); a[0] += p.x;  a[1] += p.y;
    p = __builtin_amdgcn_cvt_pk_f32_fp8(u.x, true);  a[2] += p.x;  a[3] += p.y;
    p = __builtin_amdgcn_cvt_pk_f32_fp8(u.y, false); a[4] += p.x;  a[5] += p.y;
    p = __builtin_amdgcn_cvt_pk_f32_fp8(u.y, true);  a[6] += p.x;  a[7] += p.y;
    p = __builtin_amdgcn_cvt_pk_f32_fp8(u.z, false); a[8] += p.x;  a[9] += p.y;
    p = __builtin_amdgcn_cvt_pk_f32_fp8(u.z, true);  a[10] += p.x; a[11] += p.y;
    p = __builtin_amdgcn_cvt_pk_f32_fp8(u.w, false); a[12] += p.x; a[13] += p.y;
    p = __builtin_amdgcn_cvt_pk_f32_fp8(u.w, true);  a[14] += p.x; a[15] += p.y;
}

// resident-grid barrier: all NBUCK blocks are co-resident (capacity 512>=391),
// so spinning is safe. threadfence = agent-scope release/acquire (cross-XCD).
__device__ inline void grid_bar(int* bar, int nblk) {
    __syncthreads();
    if (threadIdx.x == 0) {
        __threadfence();
        int prev = __hip_atomic_fetch_add(bar, 1, __ATOMIC_ACQ_REL,
                                          __HIP_MEMORY_SCOPE_AGENT);
        if (prev + 1 < nblk) {
            while (__hip_atomic_load(bar, __ATOMIC_ACQUIRE,
                                     __HIP_MEMORY_SCOPE_AGENT) < nblk)
                __builtin_amdgcn_s_sleep(16);
        }
        __threadfence();
    }
    __syncthreads();
}

// ---- MEGA: bucket -> matmul(own nodes, h1->LDS) -> BAR -> sort+prescale ->
//      BAR -> gather1 (stage in LDS) -> BAR -> gather2+log_softmax ----
__global__ __launch_bounds__(512, 4) void k_mega(const int* __restrict__ row,
                                                 const int* __restrict__ col,
                                                 int* __restrict__ bucket_fill,
                                                 int* __restrict__ bars,
                                                 uint32_t* __restrict__ slab,
                                                 const float* __restrict__ x,
                                                 const float* __restrict__ W1,
                                                 const float* __restrict__ b1,
                                                 const float* __restrict__ W2,
                                                 const float* __restrict__ b2,
                                                 uint32_t* __restrict__ h1q,
                                                 float* __restrict__ h2s,
                                                 float* __restrict__ out,
                                                 int e, int n) {
    __shared__ union {
        struct { int hist[NBUCK]; int base[NBUCK]; } bk;                   // 3.1 KB
        struct { uint16_t xs[128 * XPAD]; uint16_t w1t[32 * XPAD]; } mm;   // 43.5 KB
        struct { int hist[256]; int excl[256]; int wsum[4];
                 uint32_t stage[CAP]; float sb1[32]; float sW2[64]; } fi;  // 20.9 KB
    } u;
    __shared__ uint32_t h1l[256 * 16];   // own 256 nodes, bf16 x32 (16 KB)
    const int tid = threadIdx.x;
    const int b = blockIdx.x;
    const int lane = tid & 63, wave = tid >> 6;
    uint32_t* sl = slab + (size_t)b * CAP;

    // ================= phase A: coarse-bucket own 4096-edge chunk =================
    {
        int* hist = u.bk.hist;
        int* base = u.bk.base;
        const int e0 = b * CHB;
        const int m = min(CHB, e - e0);
        const bool full = (m == CHB);

        for (int i = tid; i < NBUCK; i += 512) hist[i] = 0;

        int cc[8], rr[8], pp[8];
        if (full) {
            const int4* c4 = (const int4*)(col + e0);   // e0 % 4 == 0
            const int4* r4 = (const int4*)(row + e0);
            #pragma unroll
            for (int t = 0; t < 2; ++t) {
                int4 c = c4[tid + t * 512];
                int4 r = r4[tid + t * 512];
                cc[t * 4 + 0] = c.x; cc[t * 4 + 1] = c.y;
                cc[t * 4 + 2] = c.z; cc[t * 4 + 3] = c.w;
                rr[t * 4 + 0] = r.x; rr[t * 4 + 1] = r.y;
                rr[t * 4 + 2] = r.z; rr[t * 4 + 3] = r.w;
            }
            __syncthreads();
            #pragma unroll
            for (int t = 0; t < 8; ++t)
                pp[t] = atomicAdd(&hist[cc[t] >> 8], 1);   // rank == return value
        } else {
            __syncthreads();
            #pragma unroll
            for (int t = 0; t < 8; ++t) {
                int i = tid + t * 512;
                if (i < m) {
                    cc[t] = col[e0 + i];
                    rr[t] = row[e0 + i];
                    pp[t] = atomicAdd(&hist[cc[t] >> 8], 1);
                }
            }
        }
        __syncthreads();
        // rotated reservation: de-burst per-bin global atomic chains
        for (int i = tid; i < NBUCK; i += 512) {
            int bb = (i + b * 131) % NBUCK;
            base[bb] = atomicAdd(&bucket_fill[bb], hist[bb]);
        }
        __syncthreads();
        if (full) {
            #pragma unroll
            for (int t = 0; t < 8; ++t) {
                int bb = cc[t] >> 8;
                int p = base[bb] + pp[t];
                if (p < CAP)   // statistically impossible overflow guard
                    slab[(size_t)bb * CAP + p] = ((uint32_t)rr[t] << 8) | (uint32_t)(cc[t] & 255);
            }
        } else {
            #pragma unroll
            for (int t = 0; t < 8; ++t) {
                int i = tid + t * 512;
                if (i < m) {
                    int bb = cc[t] >> 8;
                    int p = base[bb] + pp[t];
                    if (p < CAP)
                        slab[(size_t)bb * CAP + p] = ((uint32_t)rr[t] << 8) | (uint32_t)(cc[t] & 255);
                }
            }
        }
        __syncthreads();   // base[] reads done before union switches to mm
    }

    // ====== phase B: matmul OWN 256 nodes -> h1l (bf16, LDS). 2 tiles of 128 ======
    {
        uint16_t* xs = u.mm.xs;
        uint16_t* w1t = u.mm.w1t;
        for (int i = tid; i < 4096; i += 512) {          // W1^T stage (once)
            int k = i >> 5, c = i & 31;
            w1t[c * XPAD + k] = bf16_bits(W1[i]);
        }
        const float4* x4 = (const float4*)x;
        #pragma unroll
        for (int g = 0; g < 2; ++g) {
            const int nodeBase = b * 256 + g * 128;
            for (int i = tid; i < 128 * 32; i += 512) {  // x tile (128 nodes) -> bf16
                int node = i >> 5;
                int k4 = i & 31;
                float4 v = make_float4(0.f, 0.f, 0.f, 0.f);
                if (nodeBase + node < n)
                    v = x4[(size_t)(nodeBase + node) * 32 + k4];
                int bo = node * XPAD + k4 * 4;
                xs[bo + 0] = bf16_bits(v.x); xs[bo + 1] = bf16_bits(v.y);
                xs[bo + 2] = bf16_bits(v.z); xs[bo + 3] = bf16_bits(v.w);
            }
            __syncthreads();
            const int nn = lane & 15;      // node-in-16 (D col) / outcol (A row)
            const int quad = lane >> 4;
            f32x4 acc0 = {0.f, 0.f, 0.f, 0.f};
            f32x4 acc1 = {0.f, 0.f, 0.f, 0.f};
            const int xrow = (wave * 16 + nn) * XPAD;    // 8 waves x 16 nodes = 128
            #pragma unroll
            for (int s = 0; s < 4; ++s) {
                const int kof = s * 32 + quad * 8;
                short8x bfrag = *(const short8x*)&xs[xrow + kof];
                short8x a0 = *(const short8x*)&w1t[nn * XPAD + kof];          // cols 0..15
                short8x a1 = *(const short8x*)&w1t[(16 + nn) * XPAD + kof];   // cols 16..31
                acc0 = __builtin_amdgcn_mfma_f32_16x16x32_bf16(a0, bfrag, acc0, 0, 0, 0);
                acc1 = __builtin_amdgcn_mfma_f32_16x16x32_bf16(a1, bfrag, acc1, 0, 0, 0);
            }
            const int nl = g * 128 + wave * 16 + nn;     // node-in-block 0..255
            h1l[nl * 16 + 2 * quad + 0] = pack_bf2(acc0[0], acc0[1]);   // feats 4q..4q+3
            h1l[nl * 16 + 2 * quad + 1] = pack_bf2(acc0[2], acc0[3]);
            h1l[nl * 16 + 8 + 2 * quad + 0] = pack_bf2(acc1[0], acc1[1]); // feats 16+4q..
            h1l[nl * 16 + 8 + 2 * quad + 1] = pack_bf2(acc1[2], acc1[3]);
            __syncthreads();   // xs reuse in next tile
        }
    }

    grid_bar(&bars[0], NBUCK);   // slab + bucket_fill complete everywhere

    // ================= phase C: fine sort + prescale (h1q global) =================
    {
        if (tid < 256) u.fi.hist[tid] = 0;
        else if (tid < 288) u.fi.sb1[tid - 256] = b1[tid - 256];
        else if (tid < 352) u.fi.sW2[tid - 288] = W2[tid - 288];
        __syncthreads();
        const int nb = min(bucket_fill[b], CAP);

        uint32_t uu[9];   // CAP/512 = 9
        int pp[9];
        #pragma unroll
        for (int j = 0; j < 9; ++j) {
            int i = tid + j * 512;
            if (i < nb) {
                uint32_t w = sl[i];
                uu[j] = w;
                pp[j] = atomicAdd(&u.fi.hist[w & 255u], 1);   // rank == return value
            }
        }
        __syncthreads();
        int v = 0, inc = 0;
        if (tid < 256) {
            v = u.fi.hist[tid];
            inc = v;
            #pragma unroll
            for (int d = 1; d < 64; d <<= 1) {
                int t = __shfl_up(inc, d);
                if (lane >= d) inc += t;
            }
            if (lane == 63) u.fi.wsum[wave] = inc;
        }
        __syncthreads();
        if (tid == 0) {
            int a = 0;
            #pragma unroll
            for (int w = 0; w < 4; ++w) { int t = u.fi.wsum[w]; u.fi.wsum[w] = a; a += t; }
        }
        __syncthreads();
        if (tid < 256) u.fi.excl[tid] = inc - v + u.fi.wsum[wave];
        __syncthreads();
        #pragma unroll
        for (int j = 0; j < 9; ++j) {
            int i = tid + j * 512;
            if (i < nb)
                u.fi.stage[u.fi.excl[uu[j] & 255u] + pp[j]] = uu[j] >> 8;
        }
        // prescale own 256 nodes: h1q = fp8(dinv * h1l), 16 u16 words/node
        uint16_t* h1q16 = (uint16_t*)h1q;
        #pragma unroll
        for (int it = 0; it < 8; ++it) {
            int i = tid + it * 512;          // 0..4095
            int node = i >> 4, j = i & 15;
            int c = b * 256 + node;
            if (c < n) {
                float dc = rsqrtf((float)(u.fi.hist[node] + 1));
                uint32_t w = h1l[node * 16 + j];         // features 2j, 2j+1
                float lo = __uint_as_float(w << 16) * dc;
                float hi = __uint_as_float(w & 0xffff0000u) * dc;
                int pk = __builtin_amdgcn_cvt_pk_fp8_f32(lo, hi, 0, false);
                h1q16[(size_t)c * 16 + j] = (uint16_t)pk;
            }
        }
    }

    grid_bar(&bars[1], NBUCK);   // all h1q rows prescaled

    // ================= phase D: gather1 (rows from LDS stage[]) =================
    {
        const int l = tid & 1;
        const int team = tid >> 1;           // 0..255
        const int c = b * 256 + team;
        if (c < n) {
            const uint4* h4 = (const uint4*)h1q;
            float acc[16], acc2[16];
            #pragma unroll
            for (int j = 0; j < 16; ++j) { acc[j] = 0.f; acc2[j] = 0.f; }
            fp8x16_acc(acc, h4[(size_t)c * 2 + l]);   // self loop
            const int ex = u.fi.excl[team];
            const int deg = u.fi.hist[team];
            int k = 0;
            for (; k + 8 <= deg; k += 8) {
                int r[8];
                uint4 uv[8];
                #pragma unroll
                for (int t = 0; t < 8; ++t) r[t] = (int)u.fi.stage[ex + k + t];
                #pragma unroll
                for (int t = 0; t < 8; ++t) uv[t] = h4[(size_t)r[t] * 2 + l];
                #pragma unroll
                for (int t = 0; t < 8; ++t) fp8x16_acc((t & 1) ? acc2 : acc, uv[t]);
            }
            for (; k + 2 <= deg; k += 2) {
                uint4 ua = h4[(size_t)(int)u.fi.stage[ex + k] * 2 + l];
                uint4 ub = h4[(size_t)(int)u.fi.stage[ex + k + 1] * 2 + l];
                fp8x16_acc(acc, ua);
                fp8x16_acc(acc2, ub);
            }
            if (k < deg)
                fp8x16_acc(acc, h4[(size_t)(int)u.fi.stage[ex + k] * 2 + l]);
            #pragma unroll
            for (int j = 0; j < 16; ++j) acc[j] += acc2[j];

            const float dc = rsqrtf((float)(deg + 1));
            const int f0 = l * 16;
            float s0 = 0.f, s1 = 0.f;
            #pragma unroll
            for (int j = 0; j < 16; ++j) {
                float a = fmaxf(dc * acc[j] + u.fi.sb1[f0 + j], 0.f);
                s0 += a * u.fi.sW2[(f0 + j) * 2];
                s1 += a * u.fi.sW2[(f0 + j) * 2 + 1];
            }
            s0 += __shfl_xor(s0, 1);
            s1 += __shfl_xor(s1, 1);
            if (l == 0) ((float2*)h2s)[c] = make_float2(dc * s0, dc * s1);
        }
    }

    grid_bar(&bars[2], NBUCK);   // all h2s rows final

    // ================= phase E: gather2 + b2 + log_softmax =================
    {
        const float2* h2 = (const float2*)h2s;
        const int l = tid & 3;
        const int team = tid >> 2;           // 0..127
        #pragma unroll
        for (int it = 0; it < 2; ++it) {
            const int idx = it * 128 + team; // node-in-bucket 0..255
            const int c = b * 256 + idx;
            if (c < n) {
                float sx = 0.f, sy = 0.f;
                if (l == 0) { float2 s = h2[c]; sx = s.x; sy = s.y; }   // self loop
                const int ex = u.fi.excl[idx];
                const int deg = u.fi.hist[idx];
                for (int k = l; k < deg; k += 4) {
                    float2 v = h2[u.fi.stage[ex + k]];
                    sx += v.x; sy += v.y;
                }
                sx += __shfl_xor(sx, 1); sx += __shfl_xor(sx, 2);
                sy += __shfl_xor(sy, 1); sy += __shfl_xor(sy, 2);
                if (l == 0) {
                    float d = rsqrtf((float)(deg + 1));
                    float v0 = d * sx + b2[0];
                    float v1 = d * sy + b2[1];
                    float m = fmaxf(v0, v1);
                    float lg = m + logf(expf(v0 - m) + expf(v1 - m));
                    ((float2*)out)[c] = make_float2(v0 - lg, v1 - lg);
                }
            }
        }
    }
}

extern "C" void kernel_launch(void* const* d_in, const int* in_sizes, int n_in,
                              void* d_out, int out_size, void* d_ws, size_t ws_size,
                              hipStream_t stream) {
    const float* x  = (const float*)d_in[0];
    const int*   ei = (const int*)d_in[1];   // [2,E] int32
    const float* W1 = (const float*)d_in[2];
    const float* b1 = (const float*)d_in[3];
    const float* W2 = (const float*)d_in[4];
    const float* b2 = (const float*)d_in[5];
    float* out = (float*)d_out;
    char* ws = (char*)d_ws;

    const int N = GNN_N, E = GNN_E;
    const int* row = ei;
    const int* col = ei + GNN_E;

    // workspace layout (4B words) — 2,802,768 words = 11.2 MB (< 16MB proven)
    int*      bucket_fill = (int*)      ws;                       // 1024
    int*      bars        = (int*)     (ws + 4ull *    1024);     // 16
    float*    h2s         = (float*)   (ws + 4ull *    1040);     // N*2
    uint32_t* h1q         = (uint32_t*)(ws + 4ull *  201040);     // N*8 (fp8, prescaled)
    uint32_t* slab        = (uint32_t*)(ws + 4ull * 1001040);     // NBUCK*CAP = 1,801,728

    hipMemsetAsync(ws, 0, 1040 * sizeof(int), stream);   // bucket_fill + bars

    int e_arg = E, n_arg = N;
    k_mega<<<NBUCK, 512, 0, stream>>>(row, col, bucket_fill, bars, slab,
                                      x, W1, b1, W2, b2, h1q, h2s, out,
                                      e_arg, n_arg);
}

// Round 9
// 163.581 us; speedup vs baseline: 1.9945x; 1.9945x over previous
//
#include <hip/hip_runtime.h>
#include <hip/hip_bf16.h>
#include <math.h>
#include <stdint.h>

// GCN 2-layer: h1 = relu(Agg(x@W1)+b1); out = log_softmax(Agg(h1@W2)+b2)
// Agg factorized: out[i] = dinv[i]*( sum_{e: col=i} hs[row_e] + hs[i] ) + b,
// hs[j] = dinv[j]*(x@W1)[j], stored as OCP fp8-e4m3 (32 B/row, 3.2MB L2-resident).
// R20 = R0-EXACT pipeline (the only config <164us; every structural deviation
// R12-R19 regressed: fusion taxes gather occupancy, overlap's savings were
// given back in plumbing) + ONE change: h2s packed as bf16 PAIR (4B/node,
// 400KB) instead of float2 (8B, 800KB). Mechanism: k_gather2's inner loop is
// 1.6M dependent random loads over h2s — halving footprint doubles line
// utilization on the only random stream there; decode is 2 VALU in a
// latency-bound loop (free). Everything else byte-identical to R0.

#define GNN_N 100000
#define GNN_E 1600000
#define NBUCK 391     // coarse buckets: col>>8
#define CAP 4608      // slab capacity (mean ~4092, +8 sigma)
#define CHB 4096      // edges per k_bucket block (16/thread, 4x int4)

typedef float fx2 __attribute__((ext_vector_type(2)));
typedef short short8x __attribute__((ext_vector_type(8)));
typedef float f32x4 __attribute__((ext_vector_type(4)));

__device__ inline uint16_t bf16_bits(float f) {   // RNE
    uint32_t u = __float_as_uint(f);
    return (uint16_t)((u + 0x7fffu + ((u >> 16) & 1u)) >> 16);
}
__device__ inline uint32_t pack_bf2(float lo, float hi) {
    return (uint32_t)bf16_bits(lo) | ((uint32_t)bf16_bits(hi) << 16);
}

// ---- coarse bucket by col>>8, pack (row<<8)|(col&255) into slabs ----
__global__ __launch_bounds__(256) void k_bucket(const int* __restrict__ row,
                                                const int* __restrict__ col,
                                                int* __restrict__ bucket_fill,
                                                uint32_t* __restrict__ slab, int e) {
    __shared__ int hist[NBUCK];
    __shared__ int base[NBUCK];
    const int tid = threadIdx.x;
    const int e0 = blockIdx.x * CHB;
    const int m = min(CHB, e - e0);
    const bool full = (m == CHB);

    for (int i = tid; i < NBUCK; i += 256) hist[i] = 0;

    int cc[16], rr[16], pp[16];
    if (full) {
        const int4* c4 = (const int4*)(col + e0);   // e0 % 4 == 0, 16B aligned
        const int4* r4 = (const int4*)(row + e0);
        #pragma unroll
        for (int t = 0; t < 4; ++t) {
            int4 c = c4[tid + t * 256];
            int4 r = r4[tid + t * 256];
            cc[t * 4 + 0] = c.x; cc[t * 4 + 1] = c.y;
            cc[t * 4 + 2] = c.z; cc[t * 4 + 3] = c.w;
            rr[t * 4 + 0] = r.x; rr[t * 4 + 1] = r.y;
            rr[t * 4 + 2] = r.z; rr[t * 4 + 3] = r.w;
        }
        __syncthreads();
        #pragma unroll
        for (int t = 0; t < 16; ++t)
            pp[t] = atomicAdd(&hist[cc[t] >> 8], 1);   // rank == return value
    } else {
        __syncthreads();
        #pragma unroll
        for (int t = 0; t < 16; ++t) {
            int i = tid + t * 256;
            if (i < m) {
                cc[t] = col[e0 + i];
                rr[t] = row[e0 + i];
                pp[t] = atomicAdd(&hist[cc[t] >> 8], 1);
            }
        }
    }
    __syncthreads();
    // rotated reservation: de-burst per-bin global atomic chains
    for (int i = tid; i < NBUCK; i += 256) {
        int bb = (i + blockIdx.x * 131) % NBUCK;
        base[bb] = atomicAdd(&bucket_fill[bb], hist[bb]);
    }
    __syncthreads();
    if (full) {
        #pragma unroll
        for (int t = 0; t < 16; ++t) {
            int b = cc[t] >> 8;
            int p = base[b] + pp[t];
            if (p < CAP)   // statistically impossible overflow guard
                slab[(size_t)b * CAP + p] = ((uint32_t)rr[t] << 8) | (uint32_t)(cc[t] & 255);
        }
    } else {
        #pragma unroll
        for (int t = 0; t < 16; ++t) {
            int i = tid + t * 256;
            if (i < m) {
                int b = cc[t] >> 8;
                int p = base[b] + pp[t];
                if (p < CAP)
                    slab[(size_t)b * CAP + p] = ((uint32_t)rr[t] << 8) | (uint32_t)(cc[t] & 255);
            }
        }
    }
}

// ---- fine sort, 2 buckets/block; emits sorted_row, offsets (contiguous,
// cnt implicit via offsets[n] sentinel), dinv. Rank trick: no cur[] atomics. ----
__global__ __launch_bounds__(512) void k_fine(const uint32_t* __restrict__ slab,
                                              const int* __restrict__ bucket_fill,
                                              int* __restrict__ sorted_row,
                                              int* __restrict__ offsets,
                                              float* __restrict__ dinv, int n) {
    __shared__ int hist[256];
    __shared__ int excl[256];
    __shared__ int wsum[4];
    __shared__ int s_gbase;
    __shared__ uint32_t stage[CAP];
    const int tid = threadIdx.x;
    const int b0 = blockIdx.x * 2;
    const int lane = tid & 63, wave = tid >> 6;

    if (blockIdx.x == gridDim.x - 1 && tid == 511) offsets[n] = GNN_E;  // sentinel

    // wave 0: gbase = sum_{b'<b0} fill[b']
    if (tid < 64) {
        int s = 0;
        for (int i = tid; i < b0; i += 64) s += bucket_fill[i];
        #pragma unroll
        for (int m = 32; m >= 1; m >>= 1) s += __shfl_xor(s, m);
        if (tid == 0) s_gbase = s;
    }
    __syncthreads();
    int gbase = s_gbase;

    for (int pass = 0; pass < 2; ++pass) {
        const int b = b0 + pass;
        if (b >= NBUCK) break;
        const int nb = min(bucket_fill[b], CAP);
        const uint32_t* sl = slab + (size_t)b * CAP;

        if (tid < 256) hist[tid] = 0;
        __syncthreads();
        uint32_t uu[9];   // CAP/512 = 9
        int pp[9];
        #pragma unroll
        for (int j = 0; j < 9; ++j) {
            int i = tid + j * 512;
            if (i < nb) {
                uint32_t u = sl[i];
                uu[j] = u;
                pp[j] = atomicAdd(&hist[u & 255u], 1);   // rank == return value
            }
        }
        __syncthreads();
        int v = 0, inc = 0;
        if (tid < 256) {
            v = hist[tid];
            inc = v;
            #pragma unroll
            for (int d = 1; d < 64; d <<= 1) {
                int t = __shfl_up(inc, d);
                if (lane >= d) inc += t;
            }
            if (lane == 63) wsum[wave] = inc;
        }
        __syncthreads();
        if (tid == 0) {
            int a = 0;
            #pragma unroll
            for (int w = 0; w < 4; ++w) { int t = wsum[w]; wsum[w] = a; a += t; }
        }
        __syncthreads();
        if (tid < 256) {
            int ex = inc - v + wsum[wave];
            excl[tid] = ex;
            int c = b * 256 + tid;
            if (c < n) {
                offsets[c] = gbase + ex;
                dinv[c] = rsqrtf((float)(v + 1));
            }
        }
        __syncthreads();
        #pragma unroll
        for (int j = 0; j < 9; ++j) {
            int i = tid + j * 512;
            if (i < nb)
                stage[excl[uu[j] & 255u] + pp[j]] = uu[j] >> 8;
        }
        __syncthreads();
        for (int i = tid; i < nb; i += 512)
            sorted_row[gbase + i] = (int)stage[i];
        gbase += nb;
        __syncthreads();   // protect LDS reuse in next pass
    }
}

// ---- h1q[i,f] = fp8e4m3( dinv[i] * (x@W1)[i,f] ) via bf16 MFMA ----
// 256 thr = 4 waves; wave w: nodes [base+16w, base+16w+16), all 32 outcols.
// D[m=outcol][n=node]: A = W1^T (A[m=lane&15][k=quad*8+j]),
// B = x^T (B[k][n=lane&15]); C/D: col(lane&15)=node, row(quad*4+reg)=outcol.
#define XPAD 136   // 17*8: short8-aligned rows
__global__ __launch_bounds__(256) void k_matmul1(const float* __restrict__ x,
                                                 const float* __restrict__ W1,
                                                 const float* __restrict__ dinv,
                                                 uint32_t* __restrict__ h1q, int n) {
    __shared__ uint16_t xs[64 * XPAD];    // bf16 x tile   (17.4 KB)
    __shared__ uint16_t w1t[32 * XPAD];   // bf16 W1^T     (8.7 KB)
    const int tid = threadIdx.x;
    const int nodeBase = blockIdx.x * 64;

    // stage W1^T: elem i=(k,c) -> w1t[c][k]
    for (int i = tid; i < 4096; i += 256) {
        int k = i >> 5, c = i & 31;
        w1t[c * XPAD + k] = bf16_bits(W1[i]);
    }
    // stage x tile as bf16
    {
        const float4* x4 = (const float4*)x;
        for (int i = tid; i < 64 * 32; i += 256) {
            int node = i >> 5;
            int k4 = i & 31;
            float4 v = make_float4(0.f, 0.f, 0.f, 0.f);
            if (nodeBase + node < n)
                v = x4[(size_t)(nodeBase + node) * 32 + k4];
            int b = node * XPAD + k4 * 4;
            xs[b + 0] = bf16_bits(v.x); xs[b + 1] = bf16_bits(v.y);
            xs[b + 2] = bf16_bits(v.z); xs[b + 3] = bf16_bits(v.w);
        }
    }
    __syncthreads();

    const int wave = tid >> 6;
    const int lane = tid & 63;
    const int nn = lane & 15;      // node-in-tile (D col) / outcol (A row)
    const int quad = lane >> 4;
    f32x4 acc0 = {0.f, 0.f, 0.f, 0.f};
    f32x4 acc1 = {0.f, 0.f, 0.f, 0.f};
    const int xrow = (wave * 16 + nn) * XPAD;
    #pragma unroll
    for (int s = 0; s < 4; ++s) {
        const int kof = s * 32 + quad * 8;
        short8x bfrag = *(const short8x*)&xs[xrow + kof];
        short8x a0 = *(const short8x*)&w1t[nn * XPAD + kof];          // cols 0..15
        short8x a1 = *(const short8x*)&w1t[(16 + nn) * XPAD + kof];   // cols 16..31
        acc0 = __builtin_amdgcn_mfma_f32_16x16x32_bf16(a0, bfrag, acc0, 0, 0, 0);
        acc1 = __builtin_amdgcn_mfma_f32_16x16x32_bf16(a1, bfrag, acc1, 0, 0, 0);
    }
    const int gn = nodeBase + wave * 16 + nn;
    if (gn < n) {
        float d = dinv[gn];
        int w0 = 0, w1 = 0;
        w0 = __builtin_amdgcn_cvt_pk_fp8_f32(acc0[0] * d, acc0[1] * d, w0, false);
        w0 = __builtin_amdgcn_cvt_pk_fp8_f32(acc0[2] * d, acc0[3] * d, w0, true);
        w1 = __builtin_amdgcn_cvt_pk_fp8_f32(acc1[0] * d, acc1[1] * d, w1, false);
        w1 = __builtin_amdgcn_cvt_pk_fp8_f32(acc1[2] * d, acc1[3] * d, w1, true);
        h1q[(size_t)gn * 8 + quad] = (uint32_t)w0;        // outcols quad*4..+3
        h1q[(size_t)gn * 8 + 4 + quad] = (uint32_t)w1;    // outcols 16+quad*4..+3
    }
}

// acc[0..15] += fp8x16 decoded from uint4
__device__ inline void fp8x16_acc(float* a, uint4 u) {
    fx2 p;
    p = __builtin_amdgcn_cvt_pk_f32_fp8(u.x, false); a[0] += p.x;  a[1] += p.y;
    p = __builtin_amdgcn_cvt_pk_f32_fp8(u.x, true);  a[2] += p.x;  a[3] += p.y;
    p = __builtin_amdgcn_cvt_pk_f32_fp8(u.y, false); a[4] += p.x;  a[5] += p.y;
    p = __builtin_amdgcn_cvt_pk_f32_fp8(u.y, true);  a[6] += p.x;  a[7] += p.y;
    p = __builtin_amdgcn_cvt_pk_f32_fp8(u.z, false); a[8] += p.x;  a[9] += p.y;
    p = __builtin_amdgcn_cvt_pk_f32_fp8(u.z, true);  a[10] += p.x; a[11] += p.y;
    p = __builtin_amdgcn_cvt_pk_f32_fp8(u.w, false); a[12] += p.x; a[13] += p.y;
    p = __builtin_amdgcn_cvt_pk_f32_fp8(u.w, true);  a[14] += p.x; a[15] += p.y;
}

// ---- layer1 gather (fp8 rows) + relu + b1 + (a1@W2) -> h2s (bf16 pair) ----
// 2-lane team per node; lane l holds feats 16l..16l+15 (one uint4 load/row)
__global__ __launch_bounds__(256) void k_gather1(const int* __restrict__ offsets,
                                                 const int* __restrict__ sorted_row,
                                                 const uint32_t* __restrict__ h1q,
                                                 const float* __restrict__ dinv,
                                                 const float* __restrict__ b1,
                                                 const float* __restrict__ W2,
                                                 uint32_t* __restrict__ h2s, int n) {
    __shared__ float sb1[32];
    __shared__ float sW2[64];
    const int tid = threadIdx.x;
    if (tid < 32) sb1[tid] = b1[tid];
    else if (tid < 96) sW2[tid - 32] = W2[tid - 32];
    __syncthreads();

    const int l = tid & 1;
    const int node = blockIdx.x * 128 + (tid >> 1);
    if (node >= n) return;
    const uint4* h4 = (const uint4*)h1q;   // 2 uint4 per 32-feat fp8 row
    float acc[16], acc2[16];
    #pragma unroll
    for (int j = 0; j < 16; ++j) { acc[j] = 0.f; acc2[j] = 0.f; }
    fp8x16_acc(acc, h4[(size_t)node * 2 + l]);   // self loop
    const int start = offsets[node];
    const int deg = offsets[node + 1] - start;
    const int* sr = sorted_row + start;
    int k = 0;
    for (; k + 8 <= deg; k += 8) {
        int r[8];
        uint4 u[8];
        #pragma unroll
        for (int t = 0; t < 8; ++t) r[t] = sr[k + t];
        #pragma unroll
        for (int t = 0; t < 8; ++t) u[t] = h4[(size_t)r[t] * 2 + l];
        #pragma unroll
        for (int t = 0; t < 8; ++t) fp8x16_acc((t & 1) ? acc2 : acc, u[t]);
    }
    for (; k + 2 <= deg; k += 2) {
        int ra = sr[k], rb = sr[k + 1];
        uint4 ua = h4[(size_t)ra * 2 + l];
        uint4 ub = h4[(size_t)rb * 2 + l];
        fp8x16_acc(acc, ua);
        fp8x16_acc(acc2, ub);
    }
    if (k < deg)
        fp8x16_acc(acc, h4[(size_t)sr[k] * 2 + l]);
    #pragma unroll
    for (int j = 0; j < 16; ++j) acc[j] += acc2[j];

    const float dc = dinv[node];
    const int f0 = l * 16;
    float s0 = 0.f, s1 = 0.f;
    #pragma unroll
    for (int j = 0; j < 16; ++j) {
        float a = fmaxf(dc * acc[j] + sb1[f0 + j], 0.f);
        s0 += a * sW2[(f0 + j) * 2];
        s1 += a * sW2[(f0 + j) * 2 + 1];
    }
    s0 += __shfl_xor(s0, 1);
    s1 += __shfl_xor(s1, 1);
    if (l == 0) h2s[node] = pack_bf2(dc * s0, dc * s1);   // bf16 pair, 4B/node
}

// ---- layer2 gather + b2 + log_softmax; edges split across 4 lanes ----
// h2s is a packed bf16 pair: 4B random loads over a 400KB L2-resident array.
__global__ __launch_bounds__(256) void k_gather2(const int* __restrict__ offsets,
                                                 const int* __restrict__ sorted_row,
                                                 const uint32_t* __restrict__ h2s,
                                                 const float* __restrict__ dinv,
                                                 const float* __restrict__ b2,
                                                 float* __restrict__ out, int n) {
    const int tid = threadIdx.x;
    const int l = tid & 3;
    const int node = blockIdx.x * 64 + (tid >> 2);
    if (node >= n) return;
    float sx = 0.f, sy = 0.f;
    if (l == 0) {   // self loop
        uint32_t w = h2s[node];
        sx = __uint_as_float(w << 16);
        sy = __uint_as_float(w & 0xffff0000u);
    }
    const int start = offsets[node];
    const int deg = offsets[node + 1] - start;
    for (int k = l; k < deg; k += 4) {
        uint32_t w = h2s[sorted_row[start + k]];
        sx += __uint_as_float(w << 16);
        sy += __uint_as_float(w & 0xffff0000u);
    }
    sx += __shfl_xor(sx, 1); sx += __shfl_xor(sx, 2);
    sy += __shfl_xor(sy, 1); sy += __shfl_xor(sy, 2);
    if (l == 0) {
        float d = dinv[node];
        float v0 = d * sx + b2[0];
        float v1 = d * sy + b2[1];
        float m = fmaxf(v0, v1);
        float lg = m + logf(expf(v0 - m) + expf(v1 - m));
        ((float2*)out)[node] = make_float2(v0 - lg, v1 - lg);
    }
}

extern "C" void kernel_launch(void* const* d_in, const int* in_sizes, int n_in,
                              void* d_out, int out_size, void* d_ws, size_t ws_size,
                              hipStream_t stream) {
    const float* x  = (const float*)d_in[0];
    const int*   ei = (const int*)d_in[1];   // [2,E] int32
    const float* W1 = (const float*)d_in[2];
    const float* b1 = (const float*)d_in[3];
    const float* W2 = (const float*)d_in[4];
    const float* b2 = (const float*)d_in[5];
    float* out = (float*)d_out;
    char* ws = (char*)d_ws;

    const int N = GNN_N, E = GNN_E;
    const int* row = ei;
    const int* col = ei + GNN_E;

    // workspace layout (4B words) — same footprint as R0 (18.4 MB proven)
    float*    dinv        = (float*)    ws;                       // N
    int*      offsets     = (int*)     (ws + 4ull *  100000);     // N+1
    int*      bucket_fill = (int*)     (ws + 4ull *  200512);     // 512
    int*      sorted_row  = (int*)     (ws + 4ull *  201024);     // E
    uint32_t* h2s         = (uint32_t*)(ws + 4ull * 1801024);     // N (bf16 pair)
    uint32_t* h1q         = (uint32_t*)(ws + 4ull * 2001024);     // N*8 (fp8 x32)
    uint32_t* slab        = (uint32_t*)(ws + 4ull * 2801024);     // NBUCK*CAP
    // end: 4,602,752 words = 18.4 MB

    hipMemsetAsync(bucket_fill, 0, NBUCK * sizeof(int), stream);

    k_bucket <<<(E + CHB - 1) / CHB, 256, 0, stream>>>(row, col, bucket_fill, slab, E);
    k_fine   <<<(NBUCK + 1) / 2, 512, 0, stream>>>(slab, bucket_fill, sorted_row, offsets, dinv, N);
    k_matmul1<<<(N + 63) / 64, 256, 0, stream>>>(x, W1, dinv, h1q, N);
    k_gather1<<<(N + 127) / 128, 256, 0, stream>>>(offsets, sorted_row, h1q, dinv, b1, W2, h2s, N);
    k_gather2<<<(N + 63) / 64, 256, 0, stream>>>(offsets, sorted_row, h2s, dinv, b2, out, N);
}